// Round 1
// baseline (4139.178 us; speedup 1.0000x reference)
//
#include <hip/hip_runtime.h>
#include <hip/hip_fp16.h>

namespace {

constexpr int Bb = 2048;
constexpr int Tt = 512;
constexpr float LOG2PI_ = 1.8378770664093453f;

struct InPtrs { const float* p[42]; };

__device__ __forceinline__ float rcpf(float x){ return __builtin_amdgcn_rcpf(x); }
__device__ __forceinline__ float sigm(float x){ return rcpf(1.0f + __expf(-x)); }
__device__ __forceinline__ float tanh_(float x){ return 1.0f - 2.0f*rcpf(1.0f + __expf(2.0f*x)); }
__device__ __forceinline__ float dot4(float4 a, float4 b){ return a.x*b.x + a.y*b.y + a.z*b.z + a.w*b.w; }

__device__ __forceinline__ float gru_out(float a0,float a1,float a2,float g0,float g1,float g2,float h){
  const float r = sigm(a0+g0);
  const float z = sigm(a1+g1);
  const float n = tanh_(a2 + r*g2);
  return (1.f - z)*n + z*h;
}

__global__ void zero2(float* out){ if (threadIdx.x < 2) out[threadIdx.x] = 0.f; }

// ---------------- Phase 1+2: bidirectional GRU scans ----------------
// grid (B/4, 2); block 64 = 1 wave = 4 batch elems; lane j of group g owns h[elem][j]
__global__ __launch_bounds__(64) void bigru(InPtrs ip, __half* __restrict__ hf, __half* __restrict__ hb)
{
  const int lane = threadIdx.x;
  const int g = lane >> 4;
  const int j = lane & 15;
  const int dir = blockIdx.y;
  const size_t bb = (size_t)(blockIdx.x*4 + g);

  const float* __restrict__ x   = ip.p[0];
  const float* __restrict__ Wih = dir ? ip.p[6] : ip.p[2];
  const float* __restrict__ Whh = dir ? ip.p[7] : ip.p[3];
  const float* __restrict__ bih = dir ? ip.p[8] : ip.p[4];
  const float* __restrict__ bhh = dir ? ip.p[9] : ip.p[5];
  __half* __restrict__ hout = dir ? hb : hf;

  constexpr int WI = 48*68, WH = 48*20;
  constexpr int TOTF = WI + WH + 48 + 48 + 4*68 + 4*20;
  __shared__ __align__(16) float sm[TOTF];
  float* Wi_s = sm;            // [48][68] padded
  float* Wh_s = sm + WI;       // [48][20] padded
  float* bi_s = Wh_s + WH;     // [48]
  float* bh_s = bi_s + 48;     // [48]
  float* x_s  = bh_s + 48;     // [4][68]
  float* h_s  = x_s + 4*68;    // [4][20]

  for (int i = lane; i < TOTF; i += 64) sm[i] = 0.f;   // zeros pads + h init
  __syncthreads();
  for (int i = lane; i < 48*64; i += 64) Wi_s[(i>>6)*68 + (i&63)] = Wih[i];
  for (int i = lane; i < 48*16; i += 64) Wh_s[(i>>4)*20 + (i&15)] = Whh[i];
  if (lane < 48){ bi_s[lane] = bih[lane]; bh_s[lane] = bhh[lane]; }
  __syncthreads();

  float hreg = 0.f;
  for (int tt = 0; tt < Tt; ++tt){
    const int t = dir ? (Tt-1-tt) : tt;
    // stage x[b][t][0..63] for the wave's 4 elems (lane -> elem lane>>4, quad lane&15)
    *(float4*)&x_s[g*68 + j*4] = *(const float4*)(x + ((bb*Tt + (size_t)t) << 6) + j*4);
    __syncthreads();

    float a0 = bi_s[j], a1 = bi_s[j+16], a2 = bi_s[j+32];
    #pragma unroll
    for (int k = 0; k < 16; ++k){
      const float4 u = *(const float4*)&x_s[g*68 + k*4];
      a0 += dot4(u, *(const float4*)&Wi_s[(j    )*68 + k*4]);
      a1 += dot4(u, *(const float4*)&Wi_s[(j+16)*68 + k*4]);
      a2 += dot4(u, *(const float4*)&Wi_s[(j+32)*68 + k*4]);
    }
    float g0 = bh_s[j], g1 = bh_s[j+16], g2 = bh_s[j+32];
    #pragma unroll
    for (int k = 0; k < 4; ++k){
      const float4 u = *(const float4*)&h_s[g*20 + k*4];
      g0 += dot4(u, *(const float4*)&Wh_s[(j    )*20 + k*4]);
      g1 += dot4(u, *(const float4*)&Wh_s[(j+16)*20 + k*4]);
      g2 += dot4(u, *(const float4*)&Wh_s[(j+32)*20 + k*4]);
    }
    hreg = gru_out(a0,a1,a2,g0,g1,g2,hreg);
    __syncthreads();
    h_s[g*20 + j] = hreg;
    hout[((size_t)t*Bb + bb)*16 + j] = __float2half(hreg);
    __syncthreads();
  }
}

// ---------------- Phase 3: the sequential VAE step ----------------
// LDS map (floats). All matrices zero-padded so float4 reads over ragged edges are safe.
constexpr int OFF_U    = 0;                 // [4][44] : z_prev(0..9) | ctx(10..41) | 0,0
constexpr int OFF_HZ   = OFF_U    + 4*44;   // [4][20]
constexpr int OFF_HGZ  = OFF_HZ   + 4*20;
constexpr int OFF_HGR  = OFF_HGZ  + 4*20;
constexpr int OFF_HH1  = OFF_HGR  + 4*20;
constexpr int OFF_HH2  = OFF_HH1  + 4*20;
constexpr int OFF_ZT   = OFF_HH2  + 4*20;   // [4][12]
constexpr int OFF_WIZ  = OFF_ZT   + 4*12;   // [48][44] infz_Wih (42 cols)
constexpr int OFF_WHZ  = OFF_WIZ  + 48*44;  // [48][20] infz_Whh
constexpr int OFF_I1   = OFF_WHZ  + 48*20;  // [16][20]
constexpr int OFF_I2   = OFF_I1   + 16*20;
constexpr int OFF_IMU  = OFF_I2   + 16*20;  // [10][20]
constexpr int OFF_ICOV = OFF_IMU  + 10*20;
constexpr int OFF_GZI  = OFF_ICOV + 10*20;  // [48][12] genz_Wih (10 cols)
constexpr int OFF_GZH  = OFF_GZI  + 48*12;  // [48][20]
constexpr int OFF_Z1   = OFF_GZH  + 48*20;
constexpr int OFF_Z2   = OFF_Z1   + 16*20;
constexpr int OFF_ZMU  = OFF_Z2   + 16*20;
constexpr int OFF_ZCOV = OFF_ZMU  + 10*20;
constexpr int OFF_GRI  = OFF_ZCOV + 10*20;  // [48][12] genr_Wih (10 cols)
constexpr int OFF_GRH  = OFF_GRI  + 48*12;  // [48][20]
constexpr int OFF_R1   = OFF_GRH  + 48*20;  // [16][20]
constexpr int OFF_R2   = OFF_R1   + 16*20;  // [192][20]
constexpr int OFF_BIZI = OFF_R2   + 192*20;
constexpr int OFF_BIZH = OFF_BIZI + 48;
constexpr int OFF_BI1  = OFF_BIZH + 48;
constexpr int OFF_BI2  = OFF_BI1  + 16;
constexpr int OFF_BIMU = OFF_BI2  + 16;
constexpr int OFF_BICOV= OFF_BIMU + 16;
constexpr int OFF_BGZI = OFF_BICOV+ 16;
constexpr int OFF_BGZH = OFF_BGZI + 48;
constexpr int OFF_BZ1  = OFF_BGZH + 48;
constexpr int OFF_BZ2  = OFF_BZ1  + 16;
constexpr int OFF_BZMU = OFF_BZ2  + 16;
constexpr int OFF_BZCOV= OFF_BZMU + 16;
constexpr int OFF_BGRI = OFF_BZCOV+ 16;
constexpr int OFF_BGRH = OFF_BGRI + 48;
constexpr int OFF_BR1  = OFF_BGRH + 48;
constexpr int OFF_BR2  = OFF_BR1  + 16;     // 192
constexpr int SM_TOT   = OFF_BR2  + 192;    // 13632 floats = 53.25 KB

__device__ __forceinline__ float matvec16(const float* sm, int offW, int offH, int g, int j, float acc){
  #pragma unroll
  for (int k = 0; k < 4; ++k){
    const float4 u = *(const float4*)&sm[offH + g*20 + k*4];
    acc += dot4(u, *(const float4*)&sm[offW + j*20 + k*4]);
  }
  return acc;
}

__device__ __forceinline__ void mv_hh3(const float* sm, int offW, int offH, int g, int j,
                                       float& g0, float& g1, float& g2){
  #pragma unroll
  for (int k = 0; k < 4; ++k){
    const float4 u = *(const float4*)&sm[offH + g*20 + k*4];
    g0 += dot4(u, *(const float4*)&sm[offW + (j    )*20 + k*4]);
    g1 += dot4(u, *(const float4*)&sm[offW + (j+16)*20 + k*4]);
    g2 += dot4(u, *(const float4*)&sm[offW + (j+32)*20 + k*4]);
  }
}

__global__ __launch_bounds__(64) void vae_step(InPtrs ip, const __half* __restrict__ hf,
                                               const __half* __restrict__ hb, float* __restrict__ out)
{
  const int lane = threadIdx.x;
  const int g = lane >> 4;
  const int j = lane & 15;
  const size_t bb = (size_t)(blockIdx.x*4 + g);
  const float* __restrict__ x   = ip.p[0];
  const float* __restrict__ eps = ip.p[1];

  __shared__ __align__(16) float sm[SM_TOT];
  for (int i = lane; i < SM_TOT; i += 64) sm[i] = 0.f;  // zeros all pads + state buffers
  __syncthreads();
  {
    auto ldw = [&](int off, const float* src, int rows, int cols, int pitch){
      const int n = rows*cols;
      for (int i = lane; i < n; i += 64){
        const int r = i / cols, c = i - r*cols;
        sm[off + r*pitch + c] = src[i];
      }
    };
    auto ldb = [&](int off, const float* src, int n){
      for (int i = lane; i < n; i += 64) sm[off + i] = src[i];
    };
    ldw(OFF_WIZ, ip.p[10], 48, 42, 44);
    ldw(OFF_WHZ, ip.p[11], 48, 16, 20);
    ldw(OFF_I1 , ip.p[14], 16, 16, 20);
    ldw(OFF_I2 , ip.p[16], 16, 16, 20);
    ldw(OFF_IMU, ip.p[18], 10, 16, 20);
    ldw(OFF_ICOV,ip.p[20], 10, 16, 20);
    ldw(OFF_GZI, ip.p[22], 48, 10, 12);
    ldw(OFF_GZH, ip.p[23], 48, 16, 20);
    ldw(OFF_Z1 , ip.p[26], 16, 16, 20);
    ldw(OFF_Z2 , ip.p[28], 16, 16, 20);
    ldw(OFF_ZMU, ip.p[30], 10, 16, 20);
    ldw(OFF_ZCOV,ip.p[32], 10, 16, 20);
    ldw(OFF_GRI, ip.p[34], 48, 10, 12);
    ldw(OFF_GRH, ip.p[35], 48, 16, 20);
    ldw(OFF_R1 , ip.p[38], 16, 16, 20);
    ldw(OFF_R2 , ip.p[40], 192,16, 20);
    ldb(OFF_BIZI, ip.p[12], 48); ldb(OFF_BIZH, ip.p[13], 48);
    ldb(OFF_BI1 , ip.p[15], 16); ldb(OFF_BI2 , ip.p[17], 16);
    ldb(OFF_BIMU, ip.p[19], 10); ldb(OFF_BICOV,ip.p[21], 10);
    ldb(OFF_BGZI, ip.p[24], 48); ldb(OFF_BGZH, ip.p[25], 48);
    ldb(OFF_BZ1 , ip.p[27], 16); ldb(OFF_BZ2 , ip.p[29], 16);
    ldb(OFF_BZMU, ip.p[31], 10); ldb(OFF_BZCOV,ip.p[33], 10);
    ldb(OFF_BGRI, ip.p[36], 48); ldb(OFF_BGRH, ip.p[37], 48);
    ldb(OFF_BR1 , ip.p[39], 16); ldb(OFF_BR2 , ip.p[41], 192);
  }
  __syncthreads();

  float hz = 0.f, hgz = 0.f, hgr = 0.f;
  float kl_acc = 0.f, nll_acc = 0.f;

  for (int t = 0; t < Tt; ++t){
    // stage ctx = [h_right = fwd[t-1], h_left = bwd[t+1]] into u[10..41]
    float hr = 0.f, hl = 0.f;
    if (t > 0)      hr = __half2float(hf[((size_t)(t-1)*Bb + bb)*16 + j]);
    if (t < Tt-1)   hl = __half2float(hb[((size_t)(t+1)*Bb + bb)*16 + j]);
    sm[OFF_U + g*44 + 10 + j] = hr;
    sm[OFF_U + g*44 + 26 + j] = hl;
    __syncthreads();

    // ---- infz GRU:  h_z = GRU([z_prev, ctx], h_z) ----
    {
      float a0 = sm[OFF_BIZI + j], a1 = sm[OFF_BIZI + 16 + j], a2 = sm[OFF_BIZI + 32 + j];
      #pragma unroll
      for (int k = 0; k < 11; ++k){
        const float4 u = *(const float4*)&sm[OFF_U + g*44 + k*4];
        a0 += dot4(u, *(const float4*)&sm[OFF_WIZ + (j    )*44 + k*4]);
        a1 += dot4(u, *(const float4*)&sm[OFF_WIZ + (j+16)*44 + k*4]);
        a2 += dot4(u, *(const float4*)&sm[OFF_WIZ + (j+32)*44 + k*4]);
      }
      float g0 = sm[OFF_BIZH + j], g1 = sm[OFF_BIZH + 16 + j], g2 = sm[OFF_BIZH + 32 + j];
      mv_hh3(sm, OFF_WHZ, OFF_HZ, g, j, g0, g1, g2);
      hz = gru_out(a0,a1,a2,g0,g1,g2,hz);
    }
    __syncthreads();
    sm[OFF_HZ + g*20 + j] = hz;
    __syncthreads();

    // ---- inference head ----
    sm[OFF_HH1 + g*20 + j] = fmaxf(matvec16(sm, OFF_I1, OFF_HZ , g, j, sm[OFF_BI1 + j]), 0.f);
    __syncthreads();
    sm[OFF_HH2 + g*20 + j] = fmaxf(matvec16(sm, OFF_I2, OFF_HH1, g, j, sm[OFF_BI2 + j]), 0.f);
    __syncthreads();
    float qmu = 0.f, qpre = 0.f, qsig = 0.f;
    if (j < 10){
      qmu  = matvec16(sm, OFF_IMU , OFF_HH2, g, j, sm[OFF_BIMU  + j]);
      qpre = matvec16(sm, OFF_ICOV, OFF_HH2, g, j, sm[OFF_BICOV + j]);
      qsig = __expf(qpre);
    }

    // ---- genz GRU:  h_gz = GRU(z_prev, h_gz) ----
    {
      float a0 = sm[OFF_BGZI + j], a1 = sm[OFF_BGZI + 16 + j], a2 = sm[OFF_BGZI + 32 + j];
      #pragma unroll
      for (int k = 0; k < 3; ++k){                     // u[10],u[11] are ctx but weight pads are 0
        const float4 u = *(const float4*)&sm[OFF_U + g*44 + k*4];
        a0 += dot4(u, *(const float4*)&sm[OFF_GZI + (j    )*12 + k*4]);
        a1 += dot4(u, *(const float4*)&sm[OFF_GZI + (j+16)*12 + k*4]);
        a2 += dot4(u, *(const float4*)&sm[OFF_GZI + (j+32)*12 + k*4]);
      }
      float g0 = sm[OFF_BGZH + j], g1 = sm[OFF_BGZH + 16 + j], g2 = sm[OFF_BGZH + 32 + j];
      mv_hh3(sm, OFF_GZH, OFF_HGZ, g, j, g0, g1, g2);
      hgz = gru_out(a0,a1,a2,g0,g1,g2,hgz);
    }
    __syncthreads();
    sm[OFF_HGZ + g*20 + j] = hgz;
    __syncthreads();

    // ---- generative-z head ----
    sm[OFF_HH1 + g*20 + j] = fmaxf(matvec16(sm, OFF_Z1, OFF_HGZ, g, j, sm[OFF_BZ1 + j]), 0.f);
    __syncthreads();
    sm[OFF_HH2 + g*20 + j] = fmaxf(matvec16(sm, OFF_Z2, OFF_HH1, g, j, sm[OFF_BZ2 + j]), 0.f);
    __syncthreads();
    if (j < 10){
      const float pmu  = matvec16(sm, OFF_ZMU , OFF_HH2, g, j, sm[OFF_BZMU  + j]);
      const float ppre = matvec16(sm, OFF_ZCOV, OFF_HH2, g, j, sm[OFF_BZCOV + j]);
      // kl = log(p_sig/q_sig) + (q_sig^2 + (q_mu-p_mu)^2)/(2 p_sig^2) - 0.5
      const float dmu = qmu - pmu;
      kl_acc += (ppre - qpre) + (qsig*qsig + dmu*dmu) * 0.5f * __expf(-2.f*ppre) - 0.5f;
      // z_t = q_mu + q_sig * eps
      const float e  = eps[(bb*Tt + (size_t)t)*10 + j];
      const float zt = qmu + qsig*e;
      sm[OFF_ZT + g*12 + j] = zt;
      sm[OFF_U  + g*44 + j] = zt;     // becomes z_prev next step
    }
    __syncthreads();

    // ---- genr GRU:  h_gr = GRU(z_t, h_gr) ----
    {
      float a0 = sm[OFF_BGRI + j], a1 = sm[OFF_BGRI + 16 + j], a2 = sm[OFF_BGRI + 32 + j];
      #pragma unroll
      for (int k = 0; k < 3; ++k){
        const float4 u = *(const float4*)&sm[OFF_ZT + g*12 + k*4];
        a0 += dot4(u, *(const float4*)&sm[OFF_GRI + (j    )*12 + k*4]);
        a1 += dot4(u, *(const float4*)&sm[OFF_GRI + (j+16)*12 + k*4]);
        a2 += dot4(u, *(const float4*)&sm[OFF_GRI + (j+32)*12 + k*4]);
      }
      float g0 = sm[OFF_BGRH + j], g1 = sm[OFF_BGRH + 16 + j], g2 = sm[OFF_BGRH + 32 + j];
      mv_hh3(sm, OFF_GRH, OFF_HGR, g, j, g0, g1, g2);
      hgr = gru_out(a0,a1,a2,g0,g1,g2,hgr);
    }
    __syncthreads();
    sm[OFF_HGR + g*20 + j] = hgr;
    __syncthreads();

    // ---- genr output head: r = relu(h_gr@W1+b1)@W2^T + b2  (192 outs, 12 rows/lane) ----
    sm[OFF_HH1 + g*20 + j] = fmaxf(matvec16(sm, OFF_R1, OFF_HGR, g, j, sm[OFF_BR1 + j]), 0.f);
    __syncthreads();
    float racc[12];
    #pragma unroll
    for (int m = 0; m < 12; ++m) racc[m] = sm[OFF_BR2 + j + 16*m];
    #pragma unroll
    for (int k = 0; k < 4; ++k){
      const float4 u = *(const float4*)&sm[OFF_HH1 + g*20 + k*4];
      #pragma unroll
      for (int m = 0; m < 12; ++m)
        racc[m] += dot4(u, *(const float4*)&sm[OFF_R2 + (j + 16*m)*20 + k*4]);
    }

    // ---- NLL (low-rank-plus-diag gaussian), sums over d via width-16 butterfly ----
    float s1 = 0.f, s2 = 0.f, s3 = 0.f, s4 = 0.f;
    #pragma unroll
    for (int i = 0; i < 4; ++i){
      const float mu   = racc[i];        // d = j + 16i
      const float dpre = racc[4+i];
      const float wv   = racc[8+i];
      const float diag = __expf(dpre) + 1e-4f;
      const float dinv = rcpf(diag);
      const float xd   = x[((bb*Tt + (size_t)t) << 6) + j + 16*i];
      const float delta = xd - mu;
      s1 += delta*delta*dinv;
      s2 += wv*wv*dinv;
      s3 += wv*dinv*delta;
      s4 += __logf(diag);
    }
    #pragma unroll
    for (int m = 1; m < 16; m <<= 1){
      s1 += __shfl_xor(s1, m, 16);
      s2 += __shfl_xor(s2, m, 16);
      s3 += __shfl_xor(s3, m, 16);
      s4 += __shfl_xor(s4, m, 16);
    }
    const float cap    = 1.f + s2;
    const float maha   = s1 - s3*s3*rcpf(cap);
    const float logdet = s4 + __logf(cap);
    const float logp   = -0.5f*(64.f*LOG2PI_ + logdet + maha);
    nll_acc += -logp;                    // replicated 16x per elem; scaled below
  }

  // block reduction (single wave) + atomics
  #pragma unroll
  for (int m = 1; m < 64; m <<= 1){
    kl_acc  += __shfl_xor(kl_acc , m, 64);
    nll_acc += __shfl_xor(nll_acc, m, 64);
  }
  if (lane == 0){
    atomicAdd(&out[0], nll_acc * (1.f/16.f) * (1.f/(float)Bb));
    atomicAdd(&out[1], kl_acc * (1.f/(float)Bb));
  }
}

} // namespace

extern "C" void kernel_launch(void* const* d_in, const int* in_sizes, int n_in,
                              void* d_out, int out_size, void* d_ws, size_t ws_size,
                              hipStream_t stream)
{
  InPtrs ip;
  for (int i = 0; i < 42; ++i) ip.p[i] = (const float*)d_in[i];
  float* out = (float*)d_out;

  // workspace: fwd & bwd hidden states as fp16, [T][B][16] each (32 MB + 32 MB)
  __half* hf = (__half*)d_ws;
  __half* hb = hf + (size_t)Tt * Bb * 16;

  zero2<<<1, 64, 0, stream>>>(out);
  dim3 gb(Bb/4, 2);
  bigru<<<gb, 64, 0, stream>>>(ip, hf, hb);
  vae_step<<<Bb/4, 64, 0, stream>>>(ip, hf, hb, out);
}

// Round 2
// 2159.325 us; speedup vs baseline: 1.9169x; 1.9169x over previous
//
#include <hip/hip_runtime.h>

namespace {

typedef __attribute__((ext_vector_type(4))) _Float16 half4v;
typedef __attribute__((ext_vector_type(4))) float   float4v;

#define MFMA16(a,b,c) __builtin_amdgcn_mfma_f32_16x16x16f16((a),(b),(c),0,0,0)

constexpr int Bb = 2048;
constexpr int Tt = 512;
constexpr float LOG2PI_ = 1.8378770664093453f;

struct InPtrs { const float* p[42]; };

__device__ __forceinline__ float rcpf(float x){ return __builtin_amdgcn_rcpf(x); }
__device__ __forceinline__ float sigm(float x){ return rcpf(1.0f + __expf(-x)); }
__device__ __forceinline__ float tanh_(float x){ return 1.0f - 2.0f*rcpf(1.0f + __expf(2.0f*x)); }

__global__ void zero2(float* out){ if (threadIdx.x < 2) out[threadIdx.x] = 0.f; }

// GRU elementwise update: D-frags (r,z,n-input,n-hidden) -> new h (half B-frag, in place)
__device__ __forceinline__ void gru_update(const float4v& Dr, const float4v& Dz,
                                           const float4v& Dn, const float4v& Dh, half4v& hB){
  #pragma unroll
  for (int i = 0; i < 4; ++i){
    const float rr = sigm(Dr[i]);
    const float zz = sigm(Dz[i]);
    const float nn = tanh_(Dn[i] + rr*Dh[i]);
    const float hp = (float)hB[i];
    hB[i] = (_Float16)((1.f - zz)*nn + zz*hp);
  }
}

__device__ __forceinline__ half4v relu_pack(const float4v& D){
  half4v o;
  #pragma unroll
  for (int i = 0; i < 4; ++i) o[i] = (_Float16)fmaxf(D[i], 0.f);
  return o;
}

// ---------------- Phase 1: bidirectional GRU, MFMA form ----------------
// 1 wave = 16 batch elems, one direction. grid (128, 2).
__global__ __launch_bounds__(64,1) void bigru(InPtrs ip, _Float16* __restrict__ hf, _Float16* __restrict__ hb)
{
  const int l = threadIdx.x, r = l & 15, q = l >> 4;
  const int dir = blockIdx.y;
  const int base = blockIdx.x * 16;

  const float* __restrict__ x   = ip.p[0];
  const float* __restrict__ Wih = dir ? ip.p[6] : ip.p[2];
  const float* __restrict__ Whh = dir ? ip.p[7] : ip.p[3];
  const float* __restrict__ bih = dir ? ip.p[8] : ip.p[4];
  const float* __restrict__ bhh = dir ? ip.p[9] : ip.p[5];
  _Float16* __restrict__ hout = dir ? hb : hf;

  // A-fragments: Wih [48x64] -> 3 row-tiles x 4 k-tiles; Whh [48x16] -> 3 row-tiles
  half4v Wi[3][4], Wh[3];
  #pragma unroll
  for (int rt = 0; rt < 3; ++rt){
    #pragma unroll
    for (int kt = 0; kt < 4; ++kt)
      #pragma unroll
      for (int j = 0; j < 4; ++j)
        Wi[rt][kt][j] = (_Float16)Wih[(rt*16 + r)*64 + kt*16 + q*4 + j];
    #pragma unroll
    for (int j = 0; j < 4; ++j)
      Wh[rt][j] = (_Float16)Whh[(rt*16 + r)*16 + q*4 + j];
  }
  float brz0[4], brz1[4], bin[4], bhn[4];
  #pragma unroll
  for (int i = 0; i < 4; ++i){
    const int row = q*4 + i;
    brz0[i] = bih[row]      + bhh[row];
    brz1[i] = bih[16 + row] + bhh[16 + row];
    bin[i]  = bih[32 + row];
    bhn[i]  = bhh[32 + row];
  }

  const float* xrow = x + (size_t)(base + r) * Tt * 64;   // this lane's elem
  half4v hB = {0,0,0,0};
  float4v xp[4];
  {
    const int t0 = dir ? Tt-1 : 0;
    #pragma unroll
    for (int kt = 0; kt < 4; ++kt)
      xp[kt] = *(const float4v*)(xrow + t0*64 + kt*16 + q*4);
  }

  for (int tt = 0; tt < Tt; ++tt){
    const int t = dir ? Tt-1-tt : tt;
    half4v xB[4];
    #pragma unroll
    for (int kt = 0; kt < 4; ++kt)
      #pragma unroll
      for (int j = 0; j < 4; ++j) xB[kt][j] = (_Float16)xp[kt][j];
    if (tt < Tt-1){
      const int tn = dir ? t-1 : t+1;
      #pragma unroll
      for (int kt = 0; kt < 4; ++kt)
        xp[kt] = *(const float4v*)(xrow + tn*64 + kt*16 + q*4);
    }
    float4v Dr = {brz0[0],brz0[1],brz0[2],brz0[3]};
    float4v Dz = {brz1[0],brz1[1],brz1[2],brz1[3]};
    float4v Dn = {bin[0],bin[1],bin[2],bin[3]};
    float4v Dh = {bhn[0],bhn[1],bhn[2],bhn[3]};
    #pragma unroll
    for (int kt = 0; kt < 4; ++kt){
      Dr = MFMA16(Wi[0][kt], xB[kt], Dr);
      Dz = MFMA16(Wi[1][kt], xB[kt], Dz);
      Dn = MFMA16(Wi[2][kt], xB[kt], Dn);
    }
    Dr = MFMA16(Wh[0], hB, Dr);
    Dz = MFMA16(Wh[1], hB, Dz);
    Dh = MFMA16(Wh[2], hB, Dh);
    #pragma unroll
    for (int i = 0; i < 4; ++i){
      const float rr = sigm(Dr[i]);
      const float zz = sigm(Dz[i]);
      const float nn = tanh_(Dn[i] + rr*Dh[i]);
      const float hp = (float)hB[i];
      const float hv = (1.f - zz)*nn + zz*hp;
      hB[i] = (_Float16)hv;
      hout[((size_t)t*16 + q*4 + i)*Bb + base + r] = (_Float16)hv;
    }
  }
}

// ---------------- Phase 3: sequential VAE step, MFMA form ----------------
// 1 wave = 16 batch elems. grid 128.
__global__ __launch_bounds__(64,1) void vae_step(InPtrs ip, const _Float16* __restrict__ hf,
                                                 const _Float16* __restrict__ hb, float* __restrict__ out)
{
  const int l = threadIdx.x, r = l & 15, q = l >> 4;
  const int base = blockIdx.x * 16;
  const float* __restrict__ x   = ip.p[0];
  const float* __restrict__ eps = ip.p[1];

  // ---- persistent A-fragments (f16) ----
  // infz_Wih [48x42], K reordered to [z 0..9 | pad | hr cols10..25 | hl cols26..41]
  half4v WizA[3][3];
  #pragma unroll
  for (int rt = 0; rt < 3; ++rt)
    #pragma unroll
    for (int kt = 0; kt < 3; ++kt)
      #pragma unroll
      for (int j = 0; j < 4; ++j){
        const int k = kt*16 + q*4 + j;
        int c;
        if (kt == 0) c = (k < 10) ? k : -1;
        else if (kt == 1) c = 10 + (k - 16);
        else c = 26 + (k - 32);
        WizA[rt][kt][j] = (c >= 0) ? (_Float16)ip.p[10][(rt*16 + r)*42 + c] : (_Float16)0.f;
      }
  half4v WhzA[3], WgzA[3], WhgzA[3], WgrA[3], WhgrA[3];
  #pragma unroll
  for (int rt = 0; rt < 3; ++rt)
    #pragma unroll
    for (int j = 0; j < 4; ++j){
      const int k = q*4 + j;
      WhzA[rt][j]  = (_Float16)ip.p[11][(rt*16 + r)*16 + k];
      WgzA[rt][j]  = (k < 10) ? (_Float16)ip.p[22][(rt*16 + r)*10 + k] : (_Float16)0.f;
      WhgzA[rt][j] = (_Float16)ip.p[23][(rt*16 + r)*16 + k];
      WgrA[rt][j]  = (k < 10) ? (_Float16)ip.p[34][(rt*16 + r)*10 + k] : (_Float16)0.f;
      WhgrA[rt][j] = (_Float16)ip.p[35][(rt*16 + r)*16 + k];
    }
  half4v I1A, I2A, IMuA, ICovA, Z1A, Z2A, ZMuA, ZCovA, R1A, R2A[12];
  #pragma unroll
  for (int j = 0; j < 4; ++j){
    const int k = q*4 + j;
    I1A[j]  = (_Float16)ip.p[14][r*16 + k];
    I2A[j]  = (_Float16)ip.p[16][r*16 + k];
    IMuA[j] = (r < 10) ? (_Float16)ip.p[18][r*16 + k] : (_Float16)0.f;
    ICovA[j]= (r < 10) ? (_Float16)ip.p[20][r*16 + k] : (_Float16)0.f;
    Z1A[j]  = (_Float16)ip.p[26][r*16 + k];
    Z2A[j]  = (_Float16)ip.p[28][r*16 + k];
    ZMuA[j] = (r < 10) ? (_Float16)ip.p[30][r*16 + k] : (_Float16)0.f;
    ZCovA[j]= (r < 10) ? (_Float16)ip.p[32][r*16 + k] : (_Float16)0.f;
    R1A[j]  = (_Float16)ip.p[38][r*16 + k];
    #pragma unroll
    for (int m = 0; m < 12; ++m)
      R2A[m][j] = (_Float16)ip.p[40][(m*16 + r)*16 + k];
  }

  // ---- persistent biases (fp32, rows = 4q+i) ----
  const int row0 = q*4;
  float bz_rz0[4], bz_rz1[4], bz_in[4], bz_hn[4];
  float bg_rz0[4], bg_rz1[4], bg_in[4], bg_hn[4];
  float br_rz0[4], br_rz1[4], br_in[4], br_hn[4];
  float bI1v[4], bI2v[4], bIMu[4], bICov[4], bZ1v[4], bZ2v[4], bZMu[4], bZCov[4], bR1v[4], bR2v[12][4];
  #pragma unroll
  for (int i = 0; i < 4; ++i){
    const int row = row0 + i;
    bz_rz0[i] = ip.p[12][row]    + ip.p[13][row];
    bz_rz1[i] = ip.p[12][16+row] + ip.p[13][16+row];
    bz_in[i]  = ip.p[12][32+row];
    bz_hn[i]  = ip.p[13][32+row];
    bg_rz0[i] = ip.p[24][row]    + ip.p[25][row];
    bg_rz1[i] = ip.p[24][16+row] + ip.p[25][16+row];
    bg_in[i]  = ip.p[24][32+row];
    bg_hn[i]  = ip.p[25][32+row];
    br_rz0[i] = ip.p[36][row]    + ip.p[37][row];
    br_rz1[i] = ip.p[36][16+row] + ip.p[37][16+row];
    br_in[i]  = ip.p[36][32+row];
    br_hn[i]  = ip.p[37][32+row];
    bI1v[i] = ip.p[15][row];  bI2v[i] = ip.p[17][row];
    bIMu[i]  = (row < 10) ? ip.p[19][row] : 0.f;
    bICov[i] = (row < 10) ? ip.p[21][row] : 0.f;
    bZ1v[i] = ip.p[27][row];  bZ2v[i] = ip.p[29][row];
    bZMu[i]  = (row < 10) ? ip.p[31][row] : 0.f;
    bZCov[i] = (row < 10) ? ip.p[33][row] : 0.f;
    bR1v[i] = ip.p[39][row];
    #pragma unroll
    for (int m = 0; m < 12; ++m) bR2v[m][i] = ip.p[41][m*16 + row];
  }

  // ---- state ----
  half4v hzB = {0,0,0,0}, hgzB = {0,0,0,0}, hgrB = {0,0,0,0}, zB = {0,0,0,0};
  float kl_acc = 0.f, nll_acc = 0.f;

  const float* xrow = x + (size_t)(base + r) * Tt * 64;     // lane's elem (col = r)
  const float* erow = eps + (size_t)(base + r) * Tt * 10;

  // prefetched next-step inputs
  half4v hrN = {0,0,0,0}, hlN = {0,0,0,0};
  float eN[4]; float4v xN[4];
  {
    // t = 0: hr = 0; hl = bwd[1]
    #pragma unroll
    for (int j = 0; j < 4; ++j)
      hlN[j] = hb[((size_t)1*16 + q*4 + j)*Bb + base + r];
    #pragma unroll
    for (int i = 0; i < 4; ++i){
      const int row = row0 + i;
      eN[i] = (row < 10) ? erow[row] : 0.f;
    }
    #pragma unroll
    for (int m = 0; m < 4; ++m)
      xN[m] = *(const float4v*)(xrow + m*16 + q*4);
  }

  for (int t = 0; t < Tt; ++t){
    const half4v hrB = hrN, hlB = hlN;
    float ev[4]; float4v xv[4];
    #pragma unroll
    for (int i = 0; i < 4; ++i) ev[i] = eN[i];
    #pragma unroll
    for (int m = 0; m < 4; ++m) xv[m] = xN[m];

    // prefetch t+1
    if (t < Tt-1){
      const int tn = t + 1;
      #pragma unroll
      for (int j = 0; j < 4; ++j){
        hrN[j] = hf[((size_t)(tn-1)*16 + q*4 + j)*Bb + base + r];
        hlN[j] = (tn < Tt-1) ? hb[((size_t)(tn+1)*16 + q*4 + j)*Bb + base + r] : (_Float16)0.f;
      }
      #pragma unroll
      for (int i = 0; i < 4; ++i){
        const int row = row0 + i;
        eN[i] = (row < 10) ? erow[tn*10 + row] : 0.f;
      }
      #pragma unroll
      for (int m = 0; m < 4; ++m)
        xN[m] = *(const float4v*)(xrow + tn*64 + m*16 + q*4);
    }

    // ---- infz GRU (u = [z_prev | hr | hl]) ----
    float4v Dr = {bz_rz0[0],bz_rz0[1],bz_rz0[2],bz_rz0[3]};
    float4v Dz = {bz_rz1[0],bz_rz1[1],bz_rz1[2],bz_rz1[3]};
    float4v Dn = {bz_in[0],bz_in[1],bz_in[2],bz_in[3]};
    float4v Dh = {bz_hn[0],bz_hn[1],bz_hn[2],bz_hn[3]};
    Dr = MFMA16(WizA[0][0], zB, Dr); Dr = MFMA16(WizA[0][1], hrB, Dr); Dr = MFMA16(WizA[0][2], hlB, Dr);
    Dz = MFMA16(WizA[1][0], zB, Dz); Dz = MFMA16(WizA[1][1], hrB, Dz); Dz = MFMA16(WizA[1][2], hlB, Dz);
    Dn = MFMA16(WizA[2][0], zB, Dn); Dn = MFMA16(WizA[2][1], hrB, Dn); Dn = MFMA16(WizA[2][2], hlB, Dn);
    Dr = MFMA16(WhzA[0], hzB, Dr);
    Dz = MFMA16(WhzA[1], hzB, Dz);
    Dh = MFMA16(WhzA[2], hzB, Dh);

    // ---- genz GRU (input z_prev) — independent of infz ----
    float4v Er = {bg_rz0[0],bg_rz0[1],bg_rz0[2],bg_rz0[3]};
    float4v Ez = {bg_rz1[0],bg_rz1[1],bg_rz1[2],bg_rz1[3]};
    float4v En = {bg_in[0],bg_in[1],bg_in[2],bg_in[3]};
    float4v Eh = {bg_hn[0],bg_hn[1],bg_hn[2],bg_hn[3]};
    Er = MFMA16(WgzA[0], zB, Er); Er = MFMA16(WhgzA[0], hgzB, Er);
    Ez = MFMA16(WgzA[1], zB, Ez); Ez = MFMA16(WhgzA[1], hgzB, Ez);
    En = MFMA16(WgzA[2], zB, En);
    Eh = MFMA16(WhgzA[2], hgzB, Eh);

    gru_update(Dr, Dz, Dn, Dh, hzB);
    gru_update(Er, Ez, En, Eh, hgzB);

    // ---- inference head ----
    float4v H1 = {bI1v[0],bI1v[1],bI1v[2],bI1v[3]};
    H1 = MFMA16(I1A, hzB, H1);
    const half4v h1B = relu_pack(H1);
    float4v H2 = {bI2v[0],bI2v[1],bI2v[2],bI2v[3]};
    H2 = MFMA16(I2A, h1B, H2);
    const half4v h2B = relu_pack(H2);
    float4v Qmu  = {bIMu[0],bIMu[1],bIMu[2],bIMu[3]};
    float4v Qpre = {bICov[0],bICov[1],bICov[2],bICov[3]};
    Qmu  = MFMA16(IMuA,  h2B, Qmu);
    Qpre = MFMA16(ICovA, h2B, Qpre);

    // ---- generative-z head ----
    float4v G1 = {bZ1v[0],bZ1v[1],bZ1v[2],bZ1v[3]};
    G1 = MFMA16(Z1A, hgzB, G1);
    const half4v g1B = relu_pack(G1);
    float4v G2 = {bZ2v[0],bZ2v[1],bZ2v[2],bZ2v[3]};
    G2 = MFMA16(Z2A, g1B, G2);
    const half4v g2B = relu_pack(G2);
    float4v Pmu  = {bZMu[0],bZMu[1],bZMu[2],bZMu[3]};
    float4v Ppre = {bZCov[0],bZCov[1],bZCov[2],bZCov[3]};
    Pmu  = MFMA16(ZMuA,  g2B, Pmu);
    Ppre = MFMA16(ZCovA, g2B, Ppre);

    // ---- KL + reparameterize (pad rows contribute exactly 0) ----
    #pragma unroll
    for (int i = 0; i < 4; ++i){
      const float qs = __expf(Qpre[i]);
      const float dm = Qmu[i] - Pmu[i];
      kl_acc += (Ppre[i] - Qpre[i]) + (qs*qs + dm*dm)*0.5f*__expf(-2.f*Ppre[i]) - 0.5f;
      zB[i] = (_Float16)(Qmu[i] + qs*ev[i]);
    }

    // ---- genr GRU (input z_t) ----
    float4v Fr = {br_rz0[0],br_rz0[1],br_rz0[2],br_rz0[3]};
    float4v Fz = {br_rz1[0],br_rz1[1],br_rz1[2],br_rz1[3]};
    float4v Fn = {br_in[0],br_in[1],br_in[2],br_in[3]};
    float4v Fh = {br_hn[0],br_hn[1],br_hn[2],br_hn[3]};
    Fr = MFMA16(WgrA[0], zB, Fr); Fr = MFMA16(WhgrA[0], hgrB, Fr);
    Fz = MFMA16(WgrA[1], zB, Fz); Fz = MFMA16(WhgrA[1], hgrB, Fz);
    Fn = MFMA16(WgrA[2], zB, Fn);
    Fh = MFMA16(WhgrA[2], hgrB, Fh);
    gru_update(Fr, Fz, Fn, Fh, hgrB);

    // ---- genr output head + NLL ----
    float4v R1D = {bR1v[0],bR1v[1],bR1v[2],bR1v[3]};
    R1D = MFMA16(R1A, hgrB, R1D);
    const half4v r1B = relu_pack(R1D);

    float s1 = 0.f, s2 = 0.f, s3 = 0.f, s4 = 0.f;
    #pragma unroll
    for (int m = 0; m < 4; ++m){
      float4v Dmu = {bR2v[m][0],bR2v[m][1],bR2v[m][2],bR2v[m][3]};
      float4v Ddp = {bR2v[4+m][0],bR2v[4+m][1],bR2v[4+m][2],bR2v[4+m][3]};
      float4v Dw  = {bR2v[8+m][0],bR2v[8+m][1],bR2v[8+m][2],bR2v[8+m][3]};
      Dmu = MFMA16(R2A[m],   r1B, Dmu);
      Ddp = MFMA16(R2A[4+m], r1B, Ddp);
      Dw  = MFMA16(R2A[8+m], r1B, Dw);
      #pragma unroll
      for (int i = 0; i < 4; ++i){
        const float diag = __expf(Ddp[i]) + 1e-4f;
        const float dinv = rcpf(diag);
        const float delta = xv[m][i] - Dmu[i];
        const float wv = Dw[i];
        s1 += delta*delta*dinv;
        s2 += wv*wv*dinv;
        s3 += wv*dinv*delta;
        s4 += __logf(diag);
      }
    }
    // reduce across the 4 q-groups (same col): xor bits 4,5
    s1 += __shfl_xor(s1, 16, 64); s1 += __shfl_xor(s1, 32, 64);
    s2 += __shfl_xor(s2, 16, 64); s2 += __shfl_xor(s2, 32, 64);
    s3 += __shfl_xor(s3, 16, 64); s3 += __shfl_xor(s3, 32, 64);
    s4 += __shfl_xor(s4, 16, 64); s4 += __shfl_xor(s4, 32, 64);
    const float cap = 1.f + s2;
    const float maha = s1 - s3*s3*rcpf(cap);
    const float logdet = s4 + __logf(cap);
    nll_acc += 0.5f*(64.f*LOG2PI_ + logdet + maha);   // = -logp, replicated 4x per elem
  }

  // wave reduce + atomics
  #pragma unroll
  for (int m = 1; m < 64; m <<= 1){
    kl_acc  += __shfl_xor(kl_acc,  m, 64);
    nll_acc += __shfl_xor(nll_acc, m, 64);
  }
  if (l == 0){
    atomicAdd(&out[0], nll_acc * 0.25f * (1.f/(float)Bb));
    atomicAdd(&out[1], kl_acc * (1.f/(float)Bb));
  }
}

} // namespace

extern "C" void kernel_launch(void* const* d_in, const int* in_sizes, int n_in,
                              void* d_out, int out_size, void* d_ws, size_t ws_size,
                              hipStream_t stream)
{
  InPtrs ip;
  for (int i = 0; i < 42; ++i) ip.p[i] = (const float*)d_in[i];
  float* out = (float*)d_out;

  // workspace: fwd & bwd hidden states fp16, layout [T][16 dims][B] (32 MB each)
  _Float16* hf = (_Float16*)d_ws;
  _Float16* hb = hf + (size_t)Tt * 16 * Bb;

  zero2<<<1, 64, 0, stream>>>(out);
  dim3 gb(Bb/16, 2);
  bigru<<<gb, 64, 0, stream>>>(ip, hf, hb);
  vae_step<<<Bb/16, 64, 0, stream>>>(ip, hf, hb, out);
}

// Round 4
// 1637.674 us; speedup vs baseline: 2.5275x; 1.3185x over previous
//
#include <hip/hip_runtime.h>

namespace {

typedef __attribute__((ext_vector_type(4))) _Float16 half4v;
typedef __attribute__((ext_vector_type(4))) float   float4v;
typedef unsigned int u32;

#define MFMA16(a,b,c) __builtin_amdgcn_mfma_f32_16x16x16f16((a),(b),(c),0,0,0)

constexpr int Bb = 2048;
constexpr int Tt = 512;
constexpr float LOG2PI_ = 1.8378770664093453f;

struct InPtrs { const float* p[42]; };

__device__ __forceinline__ float rcpf(float x){ return __builtin_amdgcn_rcpf(x); }
__device__ __forceinline__ float sigm(float x){ return rcpf(1.0f + __expf(-x)); }
__device__ __forceinline__ float tanh_(float x){ return 1.0f - 2.0f*rcpf(1.0f + __expf(2.0f*x)); }

__global__ void zero2(float* out){ if (threadIdx.x < 2) out[threadIdx.x] = 0.f; }

__device__ __forceinline__ void gru_update(const float4v& Dr, const float4v& Dz,
                                           const float4v& Dn, const float4v& Dh, half4v& hB){
  #pragma unroll
  for (int i = 0; i < 4; ++i){
    const float rr = sigm(Dr[i]);
    const float zz = sigm(Dz[i]);
    const float nn = tanh_(Dn[i] + rr*Dh[i]);
    const float hp = (float)hB[i];
    hB[i] = (_Float16)((1.f - zz)*nn + zz*hp);
  }
}

__device__ __forceinline__ half4v relu_pack(const float4v& D){
  half4v o;
  #pragma unroll
  for (int i = 0; i < 4; ++i) o[i] = (_Float16)fmaxf(D[i], 0.f);
  return o;
}

// ================= Phase 1: bi-GRU, producer/consumer, uniform barriers =================
// grid (128, 2) x 128 threads. Wave1 produces gi = Wih@x + biases for chunk c into
// buffer c&1; barrier (block-uniform); wave0 consumes chunk c while wave1 produces c+1.
constexpr int CH = 8;
constexpr int NCH = Tt / CH;   // 64

__global__ __launch_bounds__(128,1) void bigru(InPtrs ip, _Float16* __restrict__ hf,
                                               _Float16* __restrict__ hb)
{
  const int tid = threadIdx.x;
  const int w = tid >> 6;
  const int l = tid & 63, r = l & 15, q = l >> 4;
  const int dir = blockIdx.y;
  const int base = blockIdx.x * 16;

  const float* __restrict__ x   = ip.p[0];
  const float* __restrict__ Wih = dir ? ip.p[6] : ip.p[2];
  const float* __restrict__ Whh = dir ? ip.p[7] : ip.p[3];
  const float* __restrict__ bih = dir ? ip.p[8] : ip.p[4];
  const float* __restrict__ bhh = dir ? ip.p[9] : ip.p[5];
  _Float16* __restrict__ hout = dir ? hb : hf;

  __shared__ __align__(16) float giS[2][CH][64][12];   // 48 KB

  // ---- per-wave persistent state (loaded divergently; NO barriers in branches) ----
  half4v Wi[3][4];            // producer
  float  b0[4], b1[4], b2[4];
  float4v xp[4];
  half4v Wh[3];               // consumer
  float  bh2[4];
  half4v hB = {0,0,0,0};
  const float* xrow = x + (size_t)(base + r) * Tt * 64;

  if (w == 1){
    #pragma unroll
    for (int rt = 0; rt < 3; ++rt)
      #pragma unroll
      for (int kt = 0; kt < 4; ++kt)
        #pragma unroll
        for (int j = 0; j < 4; ++j)
          Wi[rt][kt][j] = (_Float16)Wih[(rt*16 + r)*64 + kt*16 + q*4 + j];
    #pragma unroll
    for (int i = 0; i < 4; ++i){
      const int row = q*4 + i;
      b0[i] = bih[row]      + bhh[row];
      b1[i] = bih[16 + row] + bhh[16 + row];
      b2[i] = bih[32 + row];
    }
    const int t0 = dir ? Tt-1 : 0;
    #pragma unroll
    for (int kt = 0; kt < 4; ++kt)
      xp[kt] = *(const float4v*)(xrow + t0*64 + kt*16 + q*4);
  } else {
    #pragma unroll
    for (int rt = 0; rt < 3; ++rt)
      #pragma unroll
      for (int j = 0; j < 4; ++j)
        Wh[rt][j] = (_Float16)Whh[(rt*16 + r)*16 + q*4 + j];
    #pragma unroll
    for (int i = 0; i < 4; ++i) bh2[i] = bhh[32 + q*4 + i];
  }

  for (int c = 0; c < NCH; ++c){
    if (w == 1){
      // ---- produce chunk c ----
      for (int st = 0; st < CH; ++st){
        const int tg = c*CH + st;
        half4v xB[4];
        #pragma unroll
        for (int kt = 0; kt < 4; ++kt)
          #pragma unroll
          for (int j = 0; j < 4; ++j) xB[kt][j] = (_Float16)xp[kt][j];
        if (tg + 1 < Tt){
          const int tn = dir ? Tt-1-(tg+1) : tg+1;
          #pragma unroll
          for (int kt = 0; kt < 4; ++kt)
            xp[kt] = *(const float4v*)(xrow + tn*64 + kt*16 + q*4);
        }
        float4v A0 = {b0[0],b0[1],b0[2],b0[3]};
        float4v A1 = {b1[0],b1[1],b1[2],b1[3]};
        float4v A2 = {b2[0],b2[1],b2[2],b2[3]};
        #pragma unroll
        for (int kt = 0; kt < 4; ++kt){
          A0 = MFMA16(Wi[0][kt], xB[kt], A0);
          A1 = MFMA16(Wi[1][kt], xB[kt], A1);
          A2 = MFMA16(Wi[2][kt], xB[kt], A2);
        }
        float* o = &giS[c&1][st][l][0];
        *(float4v*)(o + 0) = A0;
        *(float4v*)(o + 4) = A1;
        *(float4v*)(o + 8) = A2;
      }
    }
    __syncthreads();          // block-uniform barrier
    if (w == 0){
      // ---- consume chunk c (overlaps produce of chunk c+1) ----
      for (int st = 0; st < CH; ++st){
        const int tg = c*CH + st;
        const int t = dir ? Tt-1-tg : tg;
        const float* gi = &giS[c&1][st][l][0];
        float4v A0 = *(const float4v*)(gi + 0);
        float4v A1 = *(const float4v*)(gi + 4);
        float4v A2 = *(const float4v*)(gi + 8);
        float4v Dh = {bh2[0],bh2[1],bh2[2],bh2[3]};
        A0 = MFMA16(Wh[0], hB, A0);
        A1 = MFMA16(Wh[1], hB, A1);
        Dh = MFMA16(Wh[2], hB, Dh);
        gru_update(A0, A1, A2, Dh, hB);
        *(half4v*)(hout + (((size_t)t*Bb + base + r) << 4) + q*4) = hB;
      }
    }
  }
}

// ================= Phase 3: VAE step, 3-wave skewed pipeline, uniform barriers =================
// grid 128 x 192 threads. One uniform loop; wave branches inside; one barrier/iteration.
// Wave A (step i): infz GRU + inf head + z. Wave B (step i-1): genz + KL. Wave C (step i-2): genr + NLL.
__global__ __launch_bounds__(192,1) void vae_step(InPtrs ip, const _Float16* __restrict__ hf,
                                                  const _Float16* __restrict__ hb, float* __restrict__ out)
{
  const int tid = threadIdx.x;
  const int w = tid / 64;
  const int l = tid & 63, r = l & 15, q = l >> 4;
  const int base = blockIdx.x * 16;
  const int row0 = q*4;

  __shared__ float qmuS[3][4][64];
  __shared__ float qpreS[3][4][64];
  __shared__ u32   zS[3][2][64];

  for (int i = tid; i < 3*2*64; i += 192) ((u32*)zS)[i] = 0u;
  __syncthreads();

  // ---- per-wave persistent state ----
  // wave A
  half4v WizA[3][3], WhzA[3], I1A, I2A, IMuA, ICovA;
  float bz0[4], bz1[4], bzn[4], bzh[4], bI1v[4], bI2v[4], bIMu[4], bICov[4];
  half4v hzB = {0,0,0,0}, zB = {0,0,0,0};
  half4v hrN = {0,0,0,0}, hlN = {0,0,0,0};
  float eN[4];
  // wave B
  half4v WgzA[3], WhgzA[3], Z1A, Z2A, ZMuA, ZCovA;
  float bg0[4], bg1[4], bgn[4], bgh[4], bZ1v[4], bZ2v[4], bZMu[4], bZCov[4];
  half4v hgzB = {0,0,0,0};
  float kl_acc = 0.f;
  // wave C
  half4v WgrA[3], WhgrA[3], R1A, R2A[12];
  float br0[4], br1[4], brn[4], brh[4], bR1v[4], bR2v[12][4];
  half4v hgrB = {0,0,0,0};
  float nll_acc = 0.f;
  float4v xN[4];

  const float* erow = ip.p[1] + (size_t)(base + r) * Tt * 10;
  const float* xrow = ip.p[0] + (size_t)(base + r) * Tt * 64;

  if (w == 0){
    #pragma unroll
    for (int rt = 0; rt < 3; ++rt)
      #pragma unroll
      for (int kt = 0; kt < 3; ++kt)
        #pragma unroll
        for (int j = 0; j < 4; ++j){
          const int k = kt*16 + q*4 + j;
          int c;
          if (kt == 0) c = (k < 10) ? k : -1;
          else if (kt == 1) c = 10 + (k - 16);
          else c = 26 + (k - 32);
          WizA[rt][kt][j] = (c >= 0) ? (_Float16)ip.p[10][(rt*16 + r)*42 + c] : (_Float16)0.f;
        }
    #pragma unroll
    for (int rt = 0; rt < 3; ++rt)
      #pragma unroll
      for (int j = 0; j < 4; ++j)
        WhzA[rt][j] = (_Float16)ip.p[11][(rt*16 + r)*16 + q*4 + j];
    #pragma unroll
    for (int j = 0; j < 4; ++j){
      const int k = q*4 + j;
      I1A[j]  = (_Float16)ip.p[14][r*16 + k];
      I2A[j]  = (_Float16)ip.p[16][r*16 + k];
      IMuA[j] = (r < 10) ? (_Float16)ip.p[18][r*16 + k] : (_Float16)0.f;
      ICovA[j]= (r < 10) ? (_Float16)ip.p[20][r*16 + k] : (_Float16)0.f;
    }
    #pragma unroll
    for (int i = 0; i < 4; ++i){
      const int row = row0 + i;
      bz0[i] = ip.p[12][row]    + ip.p[13][row];
      bz1[i] = ip.p[12][16+row] + ip.p[13][16+row];
      bzn[i] = ip.p[12][32+row];
      bzh[i] = ip.p[13][32+row];
      bI1v[i] = ip.p[15][row];  bI2v[i] = ip.p[17][row];
      bIMu[i]  = (row < 10) ? ip.p[19][row] : 0.f;
      bICov[i] = (row < 10) ? ip.p[21][row] : 0.f;
    }
    hlN = *(const half4v*)(hb + (((size_t)1*Bb + base + r) << 4) + q*4);
    #pragma unroll
    for (int i = 0; i < 4; ++i) eN[i] = (row0 + i < 10) ? erow[row0 + i] : 0.f;
  } else if (w == 1){
    #pragma unroll
    for (int rt = 0; rt < 3; ++rt)
      #pragma unroll
      for (int j = 0; j < 4; ++j){
        const int k = q*4 + j;
        WgzA[rt][j]  = (k < 10) ? (_Float16)ip.p[22][(rt*16 + r)*10 + k] : (_Float16)0.f;
        WhgzA[rt][j] = (_Float16)ip.p[23][(rt*16 + r)*16 + k];
      }
    #pragma unroll
    for (int j = 0; j < 4; ++j){
      const int k = q*4 + j;
      Z1A[j]  = (_Float16)ip.p[26][r*16 + k];
      Z2A[j]  = (_Float16)ip.p[28][r*16 + k];
      ZMuA[j] = (r < 10) ? (_Float16)ip.p[30][r*16 + k] : (_Float16)0.f;
      ZCovA[j]= (r < 10) ? (_Float16)ip.p[32][r*16 + k] : (_Float16)0.f;
    }
    #pragma unroll
    for (int i = 0; i < 4; ++i){
      const int row = row0 + i;
      bg0[i] = ip.p[24][row]    + ip.p[25][row];
      bg1[i] = ip.p[24][16+row] + ip.p[25][16+row];
      bgn[i] = ip.p[24][32+row];
      bgh[i] = ip.p[25][32+row];
      bZ1v[i] = ip.p[27][row];  bZ2v[i] = ip.p[29][row];
      bZMu[i]  = (row < 10) ? ip.p[31][row] : 0.f;
      bZCov[i] = (row < 10) ? ip.p[33][row] : 0.f;
    }
  } else {
    #pragma unroll
    for (int rt = 0; rt < 3; ++rt)
      #pragma unroll
      for (int j = 0; j < 4; ++j){
        const int k = q*4 + j;
        WgrA[rt][j]  = (k < 10) ? (_Float16)ip.p[34][(rt*16 + r)*10 + k] : (_Float16)0.f;
        WhgrA[rt][j] = (_Float16)ip.p[35][(rt*16 + r)*16 + k];
      }
    #pragma unroll
    for (int j = 0; j < 4; ++j){
      const int k = q*4 + j;
      R1A[j] = (_Float16)ip.p[38][r*16 + k];
      #pragma unroll
      for (int m = 0; m < 12; ++m)
        R2A[m][j] = (_Float16)ip.p[40][(m*16 + r)*16 + k];
    }
    #pragma unroll
    for (int i = 0; i < 4; ++i){
      const int row = row0 + i;
      br0[i] = ip.p[36][row]    + ip.p[37][row];
      br1[i] = ip.p[36][16+row] + ip.p[37][16+row];
      brn[i] = ip.p[36][32+row];
      brh[i] = ip.p[37][32+row];
      bR1v[i] = ip.p[39][row];
      #pragma unroll
      for (int m = 0; m < 12; ++m) bR2v[m][i] = ip.p[41][m*16 + row];
    }
    #pragma unroll
    for (int m = 0; m < 4; ++m) xN[m] = *(const float4v*)(xrow + m*16 + q*4);
  }

  // ---- the single uniform pipeline loop: one barrier per iteration ----
  for (int i = 0; i < Tt + 2; ++i){
    if (w == 0){
      if (i < Tt){
        const half4v hrB = hrN, hlB = hlN;
        float ev[4];
        #pragma unroll
        for (int ii = 0; ii < 4; ++ii) ev[ii] = eN[ii];
        if (i < Tt-1){
          const int tn = i + 1;
          hrN = *(const half4v*)(hf + (((size_t)(tn-1)*Bb + base + r) << 4) + q*4);
          if (tn < Tt-1) hlN = *(const half4v*)(hb + (((size_t)(tn+1)*Bb + base + r) << 4) + q*4);
          else { half4v zz0 = {0,0,0,0}; hlN = zz0; }
          #pragma unroll
          for (int ii = 0; ii < 4; ++ii) eN[ii] = (row0 + ii < 10) ? erow[tn*10 + row0 + ii] : 0.f;
        }
        float4v Dr = {bz0[0],bz0[1],bz0[2],bz0[3]};
        float4v Dz = {bz1[0],bz1[1],bz1[2],bz1[3]};
        float4v Dn = {bzn[0],bzn[1],bzn[2],bzn[3]};
        float4v Dh = {bzh[0],bzh[1],bzh[2],bzh[3]};
        Dr = MFMA16(WizA[0][0], zB, Dr); Dr = MFMA16(WizA[0][1], hrB, Dr); Dr = MFMA16(WizA[0][2], hlB, Dr);
        Dz = MFMA16(WizA[1][0], zB, Dz); Dz = MFMA16(WizA[1][1], hrB, Dz); Dz = MFMA16(WizA[1][2], hlB, Dz);
        Dn = MFMA16(WizA[2][0], zB, Dn); Dn = MFMA16(WizA[2][1], hrB, Dn); Dn = MFMA16(WizA[2][2], hlB, Dn);
        Dr = MFMA16(WhzA[0], hzB, Dr);
        Dz = MFMA16(WhzA[1], hzB, Dz);
        Dh = MFMA16(WhzA[2], hzB, Dh);
        gru_update(Dr, Dz, Dn, Dh, hzB);

        float4v H1 = {bI1v[0],bI1v[1],bI1v[2],bI1v[3]};
        H1 = MFMA16(I1A, hzB, H1);
        const half4v h1B = relu_pack(H1);
        float4v H2 = {bI2v[0],bI2v[1],bI2v[2],bI2v[3]};
        H2 = MFMA16(I2A, h1B, H2);
        const half4v h2B = relu_pack(H2);
        float4v Qmu  = {bIMu[0],bIMu[1],bIMu[2],bIMu[3]};
        float4v Qpre = {bICov[0],bICov[1],bICov[2],bICov[3]};
        Qmu  = MFMA16(IMuA,  h2B, Qmu);
        Qpre = MFMA16(ICovA, h2B, Qpre);

        const int slot = i % 3;
        #pragma unroll
        for (int ii = 0; ii < 4; ++ii){
          const float qs = __expf(Qpre[ii]);
          zB[ii] = (_Float16)(Qmu[ii] + qs*ev[ii]);
          qmuS[slot][ii][l]  = Qmu[ii];
          qpreS[slot][ii][l] = Qpre[ii];
        }
        union { half4v h; u32 u[2]; } zc; zc.h = zB;
        zS[slot][0][l] = zc.u[0];
        zS[slot][1][l] = zc.u[1];
      }
    } else if (w == 1){
      if (i >= 1 && i <= Tt){
        const int s = i - 1;
        const int sp = (s - 1 + 3) % 3;
        union { half4v h; u32 u[2]; } zc;
        zc.u[0] = zS[sp][0][l]; zc.u[1] = zS[sp][1][l];
        const half4v zPrev = zc.h;

        float4v Er = {bg0[0],bg0[1],bg0[2],bg0[3]};
        float4v Ez = {bg1[0],bg1[1],bg1[2],bg1[3]};
        float4v En = {bgn[0],bgn[1],bgn[2],bgn[3]};
        float4v Eh = {bgh[0],bgh[1],bgh[2],bgh[3]};
        Er = MFMA16(WgzA[0], zPrev, Er); Er = MFMA16(WhgzA[0], hgzB, Er);
        Ez = MFMA16(WgzA[1], zPrev, Ez); Ez = MFMA16(WhgzA[1], hgzB, Ez);
        En = MFMA16(WgzA[2], zPrev, En);
        Eh = MFMA16(WhgzA[2], hgzB, Eh);
        gru_update(Er, Ez, En, Eh, hgzB);

        float4v G1 = {bZ1v[0],bZ1v[1],bZ1v[2],bZ1v[3]};
        G1 = MFMA16(Z1A, hgzB, G1);
        const half4v g1B = relu_pack(G1);
        float4v G2 = {bZ2v[0],bZ2v[1],bZ2v[2],bZ2v[3]};
        G2 = MFMA16(Z2A, g1B, G2);
        const half4v g2B = relu_pack(G2);
        float4v Pmu  = {bZMu[0],bZMu[1],bZMu[2],bZMu[3]};
        float4v Ppre = {bZCov[0],bZCov[1],bZCov[2],bZCov[3]};
        Pmu  = MFMA16(ZMuA,  g2B, Pmu);
        Ppre = MFMA16(ZCovA, g2B, Ppre);

        const int sq = s % 3;
        #pragma unroll
        for (int ii = 0; ii < 4; ++ii){
          const float qmu  = qmuS[sq][ii][l];
          const float qpre = qpreS[sq][ii][l];
          const float qs = __expf(qpre);
          const float dm = qmu - Pmu[ii];
          kl_acc += (Ppre[ii] - qpre) + (qs*qs + dm*dm)*0.5f*__expf(-2.f*Ppre[ii]) - 0.5f;
        }
      }
    } else {
      if (i >= 2){
        const int u = i - 2;
        float4v xv[4];
        #pragma unroll
        for (int m = 0; m < 4; ++m) xv[m] = xN[m];
        if (u + 1 < Tt){
          #pragma unroll
          for (int m = 0; m < 4; ++m)
            xN[m] = *(const float4v*)(xrow + (u+1)*64 + m*16 + q*4);
        }
        union { half4v h; u32 uu[2]; } zc;
        zc.uu[0] = zS[u % 3][0][l]; zc.uu[1] = zS[u % 3][1][l];
        const half4v zU = zc.h;

        float4v Fr = {br0[0],br0[1],br0[2],br0[3]};
        float4v Fz = {br1[0],br1[1],br1[2],br1[3]};
        float4v Fn = {brn[0],brn[1],brn[2],brn[3]};
        float4v Fh = {brh[0],brh[1],brh[2],brh[3]};
        Fr = MFMA16(WgrA[0], zU, Fr); Fr = MFMA16(WhgrA[0], hgrB, Fr);
        Fz = MFMA16(WgrA[1], zU, Fz); Fz = MFMA16(WhgrA[1], hgrB, Fz);
        Fn = MFMA16(WgrA[2], zU, Fn);
        Fh = MFMA16(WhgrA[2], hgrB, Fh);
        gru_update(Fr, Fz, Fn, Fh, hgrB);

        float4v R1D = {bR1v[0],bR1v[1],bR1v[2],bR1v[3]};
        R1D = MFMA16(R1A, hgrB, R1D);
        const half4v r1B = relu_pack(R1D);

        float s1 = 0.f, s2 = 0.f, s3 = 0.f, s4 = 0.f;
        #pragma unroll
        for (int m = 0; m < 4; ++m){
          float4v Dmu = {bR2v[m][0],bR2v[m][1],bR2v[m][2],bR2v[m][3]};
          float4v Ddp = {bR2v[4+m][0],bR2v[4+m][1],bR2v[4+m][2],bR2v[4+m][3]};
          float4v Dw  = {bR2v[8+m][0],bR2v[8+m][1],bR2v[8+m][2],bR2v[8+m][3]};
          Dmu = MFMA16(R2A[m],   r1B, Dmu);
          Ddp = MFMA16(R2A[4+m], r1B, Ddp);
          Dw  = MFMA16(R2A[8+m], r1B, Dw);
          #pragma unroll
          for (int ii = 0; ii < 4; ++ii){
            const float diag = __expf(Ddp[ii]) + 1e-4f;
            const float dinv = rcpf(diag);
            const float delta = xv[m][ii] - Dmu[ii];
            const float wv = Dw[ii];
            s1 += delta*delta*dinv;
            s2 += wv*wv*dinv;
            s3 += wv*dinv*delta;
            s4 += __logf(diag);
          }
        }
        s1 += __shfl_xor(s1, 16, 64); s1 += __shfl_xor(s1, 32, 64);
        s2 += __shfl_xor(s2, 16, 64); s2 += __shfl_xor(s2, 32, 64);
        s3 += __shfl_xor(s3, 16, 64); s3 += __shfl_xor(s3, 32, 64);
        s4 += __shfl_xor(s4, 16, 64); s4 += __shfl_xor(s4, 32, 64);
        const float cap = 1.f + s2;
        const float maha = s1 - s3*s3*rcpf(cap);
        const float logdet = s4 + __logf(cap);
        nll_acc += 0.5f*(64.f*LOG2PI_ + logdet + maha);
      }
    }
    __syncthreads();          // block-uniform barrier
  }

  // final reductions (divergent, no barriers)
  if (w == 1){
    #pragma unroll
    for (int m = 1; m < 64; m <<= 1) kl_acc += __shfl_xor(kl_acc, m, 64);
    if (l == 0) atomicAdd(&out[1], kl_acc * (1.f/(float)Bb));
  } else if (w == 2){
    #pragma unroll
    for (int m = 1; m < 64; m <<= 1) nll_acc += __shfl_xor(nll_acc, m, 64);
    if (l == 0) atomicAdd(&out[0], nll_acc * 0.25f * (1.f/(float)Bb));
  }
}

} // namespace

extern "C" void kernel_launch(void* const* d_in, const int* in_sizes, int n_in,
                              void* d_out, int out_size, void* d_ws, size_t ws_size,
                              hipStream_t stream)
{
  InPtrs ip;
  for (int i = 0; i < 42; ++i) ip.p[i] = (const float*)d_in[i];
  float* out = (float*)d_out;

  // workspace: fwd & bwd hidden states fp16, layout [T][B][16] (32 MB each)
  _Float16* hf = (_Float16*)d_ws;
  _Float16* hb = hf + (size_t)Tt * Bb * 16;

  zero2<<<1, 64, 0, stream>>>(out);
  dim3 gb(Bb/16, 2);
  bigru<<<gb, 128, 0, stream>>>(ip, hf, hb);
  vae_step<<<Bb/16, 192, 0, stream>>>(ip, hf, hb, out);
}